// Round 2
// baseline (1040.353 us; speedup 1.0000x reference)
//
#include <hip/hip_runtime.h>
#include <cmath>

// ---- problem dims (fixed per reference) ----
#define YCH 8        // y_channels
#define NTR 16       // trials
#define LLEN 4096    // trial length
#define CK  16       // kernels per channel
#define KS  64       // kernel size
#define ENC 4033     // LLEN - KS + 1
#define NP  128      // YCH*NTR independent problems
#define INV_LIP 0.1f     // 1/10
#define THRESH 0.01f     // LAM/LIP = 0.1/10

// =====================================================================
// Kernel A: residual  res[p,t] = y[n,ch,t] - sum_{c,k} Xt[p,c,t-k]*H[ch,c,k]
// 128 threads, 8 consecutive t per thread, TT=1024 outputs/block.
// One channel staged in LDS at a time (double-buffered, reg prefetch).
// =====================================================================
#define RT_TT 1024
#define RT_THREADS 128
#define RT_W 1088          // 1024 + 64 halo
#define RT_PITCH 1104

__global__ __launch_bounds__(RT_THREADS) void resid_kernel(
    const float* __restrict__ y, const float* __restrict__ H,
    const float* __restrict__ Xt, float* __restrict__ res)
{
    __shared__ __align__(16) float xs[2][RT_PITCH];
    __shared__ __align__(16) float hs[CK][KS];
    const int tid = threadIdx.x;
    const int t0  = blockIdx.x * RT_TT;
    const int p   = blockIdx.y;
    const int n   = p & 15;
    const int ch  = p >> 4;

    for (int idx = tid; idx < CK * KS; idx += RT_THREADS)
        hs[idx >> 6][idx & 63] = H[(size_t)ch * CK * KS + idx];

    const float* xbase = Xt + (size_t)p * CK * ENC;

    // stage channel 0 into buffer 0
    #pragma unroll
    for (int s = 0; s < 9; ++s) {
        int l = tid + s * RT_THREADS;
        if (l < RT_W) {
            int gi = t0 - 63 + l;
            xs[0][l] = (gi >= 0 && gi < ENC) ? xbase[gi] : 0.f;
        }
    }
    __syncthreads();

    float acc[8] = {0.f,0.f,0.f,0.f,0.f,0.f,0.f,0.f};

    for (int c = 0; c < CK; ++c) {
        // issue prefetch of channel c+1 (global -> regs), hidden under compute
        float pre[9];
        if (c + 1 < CK) {
            const float* src = xbase + (size_t)(c + 1) * ENC;
            #pragma unroll
            for (int s = 0; s < 9; ++s) {
                int l = tid + s * RT_THREADS;
                int gi = t0 - 63 + l;
                pre[s] = (l < RT_W && gi >= 0 && gi < ENC) ? src[gi] : 0.f;
            }
        }

        // compute: acc[j] += xs[8*tid + kk + j] * h[63-kk], kk = 4g+m
        const float4* xr = (const float4*)(&xs[c & 1][0]) + 2 * tid;
        const float4* hr = (const float4*)(&hs[c][0]);
        float4 A = xr[0], B = xr[1], C4 = xr[2];
        #pragma unroll
        for (int g = 0; g < 16; ++g) {
            float4 h4 = hr[15 - g];
            float w[12]  = {A.x,A.y,A.z,A.w, B.x,B.y,B.z,B.w, C4.x,C4.y,C4.z,C4.w};
            float hh[4]  = {h4.w, h4.z, h4.y, h4.x};
            #pragma unroll
            for (int m = 0; m < 4; ++m)
                #pragma unroll
                for (int j = 0; j < 8; ++j)
                    acc[j] = fmaf(w[m + j], hh[m], acc[j]);
            A = B; B = C4;
            if (g < 15) C4 = xr[g + 3];
        }

        // commit prefetch to the other buffer
        if (c + 1 < CK) {
            #pragma unroll
            for (int s = 0; s < 9; ++s) {
                int l = tid + s * RT_THREADS;
                if (l < RT_W) xs[(c + 1) & 1][l] = pre[s];
            }
        }
        __syncthreads();
    }

    const int t = t0 + 8 * tid;
    const float* yrow = y + (size_t)(n * YCH + ch) * LLEN + t;
    float4 y0 = *(const float4*)(yrow);
    float4 y1 = *(const float4*)(yrow + 4);
    float4 r0 = make_float4(y0.x - acc[0], y0.y - acc[1], y0.z - acc[2], y0.w - acc[3]);
    float4 r1 = make_float4(y1.x - acc[4], y1.y - acc[5], y1.z - acc[6], y1.w - acc[7]);
    float* rrow = res + (size_t)p * LLEN + t;
    *(float4*)(rrow)     = r0;
    *(float4*)(rrow + 4) = r1;
}

// =====================================================================
// Kernel B: analysis conv + FISTA update
//   g[c,i] = sum_k rs[i+k]*(H[ch,c,k]/LIP)
//   x_new  = relu(x_tmp + g - LAM/LIP); x_tmpNew = x_new + beta*(x_new-x_old)
// 128 threads, 8 consecutive i per thread, TI=1024.
// =====================================================================
#define FT_TI 1024
#define FT_THREADS 128
#define FT_W 1088

__global__ __launch_bounds__(FT_THREADS) void fista_kernel(
    const float* __restrict__ rsrc, int rsrc_is_y,
    const float* __restrict__ H,
    float* __restrict__ Xo, float* __restrict__ Xt,
    float beta, int first, int write_tmp)
{
    __shared__ __align__(16) float rs[FT_W];
    __shared__ __align__(16) float hs[CK][KS];
    const int tid = threadIdx.x;
    const int i0  = blockIdx.x * FT_TI;
    const int p   = blockIdx.y;
    const int n   = p & 15;
    const int ch  = p >> 4;

    for (int idx = tid; idx < CK * KS; idx += FT_THREADS)
        hs[idx >> 6][idx & 63] = H[(size_t)ch * CK * KS + idx] * INV_LIP;

    const size_t roff = rsrc_is_y ? (size_t)(n * YCH + ch) * LLEN
                                  : (size_t)p * LLEN;
    #pragma unroll
    for (int s = 0; s < 9; ++s) {
        int l = tid + s * FT_THREADS;
        if (l < FT_W) {
            int gi = i0 + l;
            rs[l] = (gi < LLEN) ? rsrc[roff + gi] : 0.f;
        }
    }
    __syncthreads();

    const int i = i0 + 8 * tid;
    const float4* rr = (const float4*)(&rs[0]) + 2 * tid;

    for (int c = 0; c < CK; ++c) {
        float acc[8] = {0.f,0.f,0.f,0.f,0.f,0.f,0.f,0.f};
        const float4* hr = (const float4*)(&hs[c][0]);
        float4 A = rr[0], B = rr[1], C4 = rr[2];
        #pragma unroll
        for (int g = 0; g < 16; ++g) {
            float4 h4 = hr[g];
            float w[12] = {A.x,A.y,A.z,A.w, B.x,B.y,B.z,B.w, C4.x,C4.y,C4.z,C4.w};
            float hh[4] = {h4.x, h4.y, h4.z, h4.w};
            #pragma unroll
            for (int m = 0; m < 4; ++m)
                #pragma unroll
                for (int j = 0; j < 8; ++j)
                    acc[j] = fmaf(w[m + j], hh[m], acc[j]);
            A = B; B = C4;
            if (g < 15) C4 = rr[g + 3];
        }

        if (i < ENC) {
            const size_t idx = (size_t)(p * CK + c) * ENC + i;
            #pragma unroll
            for (int j = 0; j < 8; ++j) {
                if (i + j < ENC) {
                    float xt = first ? 0.f : Xt[idx + j];
                    float xo = first ? 0.f : Xo[idx + j];
                    float xn = fmaxf(xt + acc[j] - THRESH, 0.f);
                    Xo[idx + j] = xn;
                    if (write_tmp) Xt[idx + j] = xn + beta * (xn - xo);
                }
            }
        }
    }
}

// =====================================================================
extern "C" void kernel_launch(void* const* d_in, const int* in_sizes, int n_in,
                              void* d_out, int out_size, void* d_ws, size_t ws_size,
                              hipStream_t stream) {
    const float* y = (const float*)d_in[0];   // [NTR, YCH, LLEN]
    const float* H = (const float*)d_in[1];   // [YCH, CK, 1, KS]
    float* Xo  = (float*)d_out;               // x_old / x_new  [p, c, i]
    float* Xt  = (float*)d_ws;                // x_tmp          [p, c, i]
    float* res = Xt + (size_t)NP * CK * ENC;  // [p, 4096]

    dim3 gA(LLEN / RT_TT, NP), bA(RT_THREADS);
    dim3 gB((ENC + FT_TI - 1) / FT_TI, NP), bB(FT_THREADS);

    float s = 1.f;
    for (int step = 0; step < 10; ++step) {
        float s_new = 0.5f * (1.f + sqrtf(1.f + 4.f * s * s));
        float beta  = (s - 1.f) / s_new;   // 0 at step 0
        s = s_new;
        if (step == 0) {
            // x_tmp = 0  =>  res = y ; fuse into the update kernel
            fista_kernel<<<gB, bB, 0, stream>>>(y, 1, H, Xo, Xt, beta, 1, 1);
        } else {
            resid_kernel<<<gA, bA, 0, stream>>>(y, H, Xt, res);
            fista_kernel<<<gB, bB, 0, stream>>>(res, 0, H, Xo, Xt, beta, 0,
                                                (step < 9) ? 1 : 0);
        }
    }
}

// Round 3
// 688.811 us; speedup vs baseline: 1.5104x; 1.5104x over previous
//
#include <hip/hip_runtime.h>
#include <cmath>

// ---- problem dims (fixed per reference) ----
#define YCH 8        // y_channels
#define NTR 16       // trials
#define LLEN 4096    // trial length
#define CK  16       // kernels per channel
#define KS  64       // kernel size
#define ENC 4033     // LLEN - KS + 1
#define NP  128      // YCH*NTR independent problems
#define INV_LIP 0.1f     // 1/10
#define THRESH 0.01f     // LAM/LIP = 0.1/10

#define R_THREADS 256
#define R_TT 1024
#define F_THREADS 256
#define F_TI 1024
#define XW4 272          // staged float4 count (1088 floats)

// B over [gi4, gi4+3], zero outside [0, ENC):  B = a + gamma*(a - p)
__device__ __forceinline__ float4 loadB4(const float* __restrict__ A,
                                         const float* __restrict__ P,
                                         float gamma, size_t coff, int gi4)
{
    if (gi4 >= 0 && gi4 + 3 < ENC) {
        float4 a = *(const float4*)(A + coff + gi4);
        float4 p = *(const float4*)(P + coff + gi4);
        return make_float4(fmaf(gamma, a.x - p.x, a.x),
                           fmaf(gamma, a.y - p.y, a.y),
                           fmaf(gamma, a.z - p.z, a.z),
                           fmaf(gamma, a.w - p.w, a.w));
    }
    float r[4];
    #pragma unroll
    for (int j = 0; j < 4; ++j) {
        int gi = gi4 + j;
        if (gi >= 0 && gi < ENC) {
            float a = A[coff + gi], p = P[coff + gi];
            r[j] = fmaf(gamma, a - p, a);
        } else r[j] = 0.f;
    }
    return make_float4(r[0], r[1], r[2], r[3]);
}

// =====================================================================
// resid: res[p,t] = y[n,ch,t] - sum_{c,k} B[p,c,t-k]*H[ch,c,k]
// grid (4, NP) x 256 thr, 4 outputs/thread, B formed on the fly.
// =====================================================================
__global__ __launch_bounds__(R_THREADS) void resid_kernel(
    const float* __restrict__ y, const float* __restrict__ H,
    const float* __restrict__ Acur, const float* __restrict__ Aprev,
    float gamma, float* __restrict__ res)
{
    __shared__ __align__(16) float xs[2][XW4 * 4];   // [t0-64, t0+1024)
    __shared__ __align__(16) float hs[CK * KS];
    const int tid = threadIdx.x;
    const int t0  = blockIdx.x * R_TT;
    const int p   = blockIdx.y;
    const int n   = p & 15, ch = p >> 4;

    ((float4*)hs)[tid] = ((const float4*)(H + (size_t)ch * CK * KS))[tid];

    const size_t pbase = (size_t)p * CK * ENC;

    // stage channel 0 into buffer 0
    #pragma unroll
    for (int s = 0; s < 2; ++s) {
        int l4 = tid + 256 * s;
        if (l4 < XW4)
            ((float4*)xs[0])[l4] = loadB4(Acur, Aprev, gamma, pbase, t0 - 64 + 4 * l4);
    }
    __syncthreads();

    float acc[4] = {0.f, 0.f, 0.f, 0.f};

    for (int c = 0; c < CK; ++c) {
        // prefetch channel c+1 (global -> regs), hidden under compute
        float4 pf0 = make_float4(0,0,0,0), pf1 = make_float4(0,0,0,0);
        bool have1 = false;
        if (c + 1 < CK) {
            size_t coff = pbase + (size_t)(c + 1) * ENC;
            pf0 = loadB4(Acur, Aprev, gamma, coff, t0 - 64 + 4 * tid);
            int l4 = tid + 256;
            if (l4 < XW4) { pf1 = loadB4(Acur, Aprev, gamma, coff, t0 - 64 + 4 * l4); have1 = true; }
        }

        // register window: xs[4*tid .. 4*tid+67] (local), output t = t0+4*tid+j
        float wf[68];
        const float4* xr = (const float4*)(xs[c & 1]) + tid;
        #pragma unroll
        for (int q = 0; q < 17; ++q) {
            float4 t4 = xr[q];
            wf[4*q] = t4.x; wf[4*q+1] = t4.y; wf[4*q+2] = t4.z; wf[4*q+3] = t4.w;
        }
        const float4* hc = (const float4*)(hs + c * KS);
        #pragma unroll
        for (int g = 0; g < 16; ++g) {
            float4 h4 = hc[g];
            float hh[4] = {h4.x, h4.y, h4.z, h4.w};
            #pragma unroll
            for (int m = 0; m < 4; ++m) {
                const int k = 4 * g + m;    // tap index
                #pragma unroll
                for (int j = 0; j < 4; ++j)  // local idx = 64 + j - k  (in [1,67])
                    acc[j] = fmaf(wf[64 + j - k], hh[m], acc[j]);
            }
        }

        if (c + 1 < CK) {
            ((float4*)xs[(c + 1) & 1])[tid] = pf0;
            if (have1) ((float4*)xs[(c + 1) & 1])[tid + 256] = pf1;
        }
        __syncthreads();
    }

    const int t = t0 + 4 * tid;
    float4 yv = *(const float4*)(y + (size_t)(n * YCH + ch) * LLEN + t);
    *(float4*)(res + (size_t)p * LLEN + t) =
        make_float4(yv.x - acc[0], yv.y - acc[1], yv.z - acc[2], yv.w - acc[3]);
}

// =====================================================================
// fista: g[c,i] = sum_k rs[i+k]*H[ch,c,k];
//        x_new = relu(B + g/LIP - thr);  write Anext only.
// Register window hoisted across all 16 channels (res is c-independent).
// grid (4, NP) x 256 thr, 4 outputs/thread.
// =====================================================================
__global__ __launch_bounds__(F_THREADS) void fista_kernel(
    const float* __restrict__ rsrc, int rsrc_is_y,
    const float* __restrict__ H,
    const float* __restrict__ Acur, const float* __restrict__ Aprev,
    float gamma, int first, float* __restrict__ Anext)
{
    __shared__ __align__(16) float rs[XW4 * 4];
    __shared__ __align__(16) float hs[CK * KS];
    const int tid = threadIdx.x;
    const int i0  = blockIdx.x * F_TI;
    const int p   = blockIdx.y;
    const int n   = p & 15, ch = p >> 4;

    ((float4*)hs)[tid] = ((const float4*)(H + (size_t)ch * CK * KS))[tid];

    const size_t roff = rsrc_is_y ? (size_t)(n * YCH + ch) * LLEN
                                  : (size_t)p * LLEN;
    #pragma unroll
    for (int s = 0; s < 2; ++s) {
        int l4 = tid + 256 * s;
        if (l4 < XW4) {
            int gi4 = i0 + 4 * l4;
            float4 v;
            if (gi4 + 3 < LLEN) {
                v = *(const float4*)(rsrc + roff + gi4);
            } else {
                float r[4];
                #pragma unroll
                for (int j = 0; j < 4; ++j)
                    r[j] = (gi4 + j < LLEN) ? rsrc[roff + gi4 + j] : 0.f;
                v = make_float4(r[0], r[1], r[2], r[3]);
            }
            ((float4*)rs)[l4] = v;
        }
    }
    __syncthreads();

    // hoisted register window rs[4*tid .. 4*tid+67]
    float wf[68];
    const float4* rr = (const float4*)rs + tid;
    #pragma unroll
    for (int q = 0; q < 17; ++q) {
        float4 t4 = rr[q];
        wf[4*q] = t4.x; wf[4*q+1] = t4.y; wf[4*q+2] = t4.z; wf[4*q+3] = t4.w;
    }

    const int i = i0 + 4 * tid;
    const size_t pbase = (size_t)p * CK * ENC;
    const bool vec = (i + 3 < ENC);

    float4 a0 = make_float4(0,0,0,0), p0 = make_float4(0,0,0,0);
    if (!first && vec) {
        a0 = *(const float4*)(Acur + pbase + i);
        p0 = *(const float4*)(Aprev + pbase + i);
    }

    for (int c = 0; c < CK; ++c) {
        float4 a1 = make_float4(0,0,0,0), p1 = make_float4(0,0,0,0);
        if (!first && vec && c + 1 < CK) {
            a1 = *(const float4*)(Acur + pbase + (size_t)(c + 1) * ENC + i);
            p1 = *(const float4*)(Aprev + pbase + (size_t)(c + 1) * ENC + i);
        }

        float acc[4] = {0.f, 0.f, 0.f, 0.f};
        const float4* hc = (const float4*)(hs + c * KS);
        #pragma unroll
        for (int g = 0; g < 16; ++g) {
            float4 h4 = hc[g];
            float hh[4] = {h4.x, h4.y, h4.z, h4.w};
            #pragma unroll
            for (int m = 0; m < 4; ++m) {
                const int k = 4 * g + m;
                #pragma unroll
                for (int j = 0; j < 4; ++j)
                    acc[j] = fmaf(wf[k + j], hh[m], acc[j]);
            }
        }

        const size_t idx = pbase + (size_t)c * ENC + i;
        if (vec) {
            float B[4] = {0.f, 0.f, 0.f, 0.f};
            if (!first) {
                float av[4] = {a0.x, a0.y, a0.z, a0.w};
                float pv[4] = {p0.x, p0.y, p0.z, p0.w};
                #pragma unroll
                for (int j = 0; j < 4; ++j) B[j] = fmaf(gamma, av[j] - pv[j], av[j]);
            }
            float4 o;
            o.x = fmaxf(fmaf(acc[0], INV_LIP, B[0]) - THRESH, 0.f);
            o.y = fmaxf(fmaf(acc[1], INV_LIP, B[1]) - THRESH, 0.f);
            o.z = fmaxf(fmaf(acc[2], INV_LIP, B[2]) - THRESH, 0.f);
            o.w = fmaxf(fmaf(acc[3], INV_LIP, B[3]) - THRESH, 0.f);
            *(float4*)(Anext + idx) = o;
        } else if (i < ENC) {
            #pragma unroll
            for (int j = 0; j < 4; ++j) {
                if (i + j < ENC) {
                    float B = 0.f;
                    if (!first) {
                        float a = Acur[idx + j], pp = Aprev[idx + j];
                        B = fmaf(gamma, a - pp, a);
                    }
                    Anext[idx + j] = fmaxf(fmaf(acc[j], INV_LIP, B) - THRESH, 0.f);
                }
            }
        }
        a0 = a1; p0 = p1;
    }
}

// =====================================================================
extern "C" void kernel_launch(void* const* d_in, const int* in_sizes, int n_in,
                              void* d_out, int out_size, void* d_ws, size_t ws_size,
                              hipStream_t stream)
{
    const float* y = (const float*)d_in[0];   // [NTR, YCH, LLEN]
    const float* H = (const float*)d_in[1];   // [YCH, CK, 1, KS]
    float* bufA = (float*)d_ws;               // A_t for even t
    float* bufB = (float*)d_out;              // A_t for odd t  (A9 -> d_out)
    float* res  = bufA + (size_t)NP * CK * ENC;

    // s-sequence and momentum gammas on host
    double s[11]; s[0] = 1.0;
    for (int t = 1; t <= 10; ++t) s[t] = 0.5 * (1.0 + sqrt(1.0 + 4.0 * s[t-1] * s[t-1]));

    dim3 gR(LLEN / R_TT, NP), gF((ENC + F_TI - 1) / F_TI, NP);

    for (int t = 0; t < 10; ++t) {
        float gamma = (t == 0) ? 0.f : (float)((s[t-1] - 1.0) / s[t]);
        float* Anext       = (t & 1) ? bufB : bufA;
        const float* Acur  = (t & 1) ? bufA : bufB;   // A_{t-1}
        const float* Aprev = (t <= 1) ? Acur           // gamma==0, value unused
                                      : ((t & 1) ? bufB : bufA);  // A_{t-2}
        if (t == 0) {
            // B_0 = 0, res = y: fuse into update kernel
            fista_kernel<<<gF, F_THREADS, 0, stream>>>(y, 1, H, bufA, bufA, 0.f, 1, bufA);
        } else {
            resid_kernel<<<gR, R_THREADS, 0, stream>>>(y, H, Acur, Aprev, gamma, res);
            fista_kernel<<<gF, F_THREADS, 0, stream>>>(res, 0, H, Acur, Aprev, gamma, 0, Anext);
        }
    }
}